// Round 10
// baseline (41.461 us; speedup 1.0000x reference)
//
#include <hip/hip_runtime.h>

// CondConv2d B=16,CIN=COUT=128,H=W=56,E=4,3x3,pad=1 fp32.
// (1) mix: fold routing into bf16 Wmix[b][cc][tap][co][ci_l] (conv linear in W).
// (2) conv: block=(b,h-pair): 128co x 128px x K=1152 GEMM on mfma_32x32x16_bf16.
//     A: global->REGISTER prefetch, depth-2 (3 rotating sets, compiler-managed
//        waitcnts; sched_barrier pins issue slots). No LDS for A.
//     B: x staged fp32->bf16 into LDS once per ci-chunk; row stride 72B makes
//        every b128 access the 8-cycle structural minimum (no swizzle needed).
//     Barriers ONLY at ci-chunk boundaries (8 total, was 36).

typedef float  f32x16 __attribute__((ext_vector_type(16)));
typedef short  s16x8  __attribute__((ext_vector_type(8)));
typedef unsigned short u16;

#define CIN   128
#define COUT  128
#define HH    56
#define WW    56
#define SP    (HH*WW)          // 3136
#define EW    147456           // per-expert W elems
#define BW_   147456           // per-sample Wmix elems: [cc4][tap9][co128][ci32]
#define XSTR  72               // xbuf row stride bytes (64 data + 8 pad)

static __device__ __forceinline__ u16 f2bf(float f) {
    unsigned u = __builtin_bit_cast(unsigned, f);
    return (u16)((u + 0x7FFFu + ((u >> 16) & 1u)) >> 16);
}

// ---------------------------------------------------------------------------
// mix: Wmix[b][cc][tap][co][ci_l] = sum_e r[b,e]*W[e][co][cc*32+ci_l][tap]
// ---------------------------------------------------------------------------
__global__ __launch_bounds__(256) void mix_kernel(const float* __restrict__ W,
                                                  const float* __restrict__ r,
                                                  u16* __restrict__ Wmix) {
    int o = blockIdx.x * 256 + threadIdx.x;      // [0, 147456)
    int ci_l = o & 31;
    int o2   = o >> 5;
    int co   = o2 & 127;
    int o3   = o2 >> 7;                          // [0,36)
    int tap  = o3 % 9;
    int cc   = o3 / 9;
    size_t src = ((size_t)co * CIN + cc*32 + ci_l) * 9 + tap;
    float w0 = W[src], w1 = W[src + EW], w2 = W[src + 2*EW], w3 = W[src + 3*EW];
    #pragma unroll
    for (int b = 0; b < 16; ++b) {
        float acc = r[b*4+0]*w0 + r[b*4+1]*w1 + r[b*4+2]*w2 + r[b*4+3]*w3;
        Wmix[(size_t)b * BW_ + o] = f2bf(acc);
    }
}

// ---------------------------------------------------------------------------
// conv: block=(b, h-pair ph). 4 waves = 2(co wm) x 2(row wn); wave 64co x 64px.
// 36 windows (cc,tap): A-regs prefetched 2 ahead; 4 ds_read_b128 + 8 MFMA.
// xbuf[4 rows][66 cols][72B] bf16, restaged per cc behind barrier pair.
// ---------------------------------------------------------------------------
__global__ __launch_bounds__(256, 3) void conv_mfma(const float* __restrict__ x,
                                                    const u16* __restrict__ Wmix,
                                                    float* __restrict__ out) {
    __shared__ __align__(16) char ldsb[4 * 66 * XSTR];   // 19,008 B

    const int bid = blockIdx.x;
    const int bs  = (bid & 7) * 56 + (bid >> 3);     // bijective XCD swizzle (448=8*56)
    const int b   = bs / 28;
    const int ph  = bs % 28;                         // rows {2ph, 2ph+1}
    const int t    = threadIdx.x;
    const int lane = t & 63;
    const int wid  = t >> 6;
    const int wm   = wid >> 1;                       // co half
    const int wn   = wid & 1;                        // output row within pair
    const int l31  = lane & 31;
    const int khalf= lane >> 5;

    const u16*   WmixB = Wmix + (size_t)b * BW_;
    const float* xbB   = x + (size_t)b * CIN * SP;

    f32x16 acc[2][2];
    #pragma unroll
    for (int mf = 0; mf < 2; ++mf)
        #pragma unroll
        for (int nf = 0; nf < 2; ++nf) acc[mf][nf] = (f32x16)0.f;

    // ---- B staging: xbuf[row 0..3][col 0..65][32 ci] for ci-chunk cc ----
    const int sc   = 1 + (t & 63);                   // col 1..64
    const int srow = t >> 6;                         // 0..3 (one row per wave)
    const int srr  = 2*ph - 1 + srow;                // input row
    const int sw   = sc - 1;                         // input col
    const bool sok = ((unsigned)srr < 56u) && (sw < 56);
    const float* sp = xbB + (size_t)srr * 56 + sw;   // + (cc*32+i*8+j)*SP
    char* sdst = ldsb + (srow*66 + sc) * XSTR;

    auto stageX = [&](int cc) {
        #pragma unroll
        for (int i = 0; i < 4; ++i) {
            s16x8 v;
            #pragma unroll
            for (int j = 0; j < 8; ++j) {
                float f = sok ? sp[(size_t)(cc*32 + i*8 + j) * SP] : 0.f;
                v[j] = (short)f2bf(f);
            }
            *(s16x8*)(sdst + i*16) = v;
        }
    };

    // ---- A prefetch: 3 rotating register sets of 4 s16x8 ----
    const u16* abase = WmixB + (wm*64 + l31)*32 + khalf*8;
    s16x8 aset[3][4];
#define ALOAD(IT, S) {                                             \
    const u16* ap_ = abase + (IT)*4096;                            \
    aset[S][0] = *(const s16x8*)(ap_);            /* mf0 ksub0 */  \
    aset[S][1] = *(const s16x8*)(ap_ + 16);       /* mf0 ksub1 */  \
    aset[S][2] = *(const s16x8*)(ap_ + 1024);     /* mf1 ksub0 */  \
    aset[S][3] = *(const s16x8*)(ap_ + 1040); }   /* mf1 ksub1 */

    // ---- prologue: zero halo cols; A(0),A(1); xbuf chunk 0 ----
    if (t < 32) {
        int row = t >> 3, col = ((t >> 2) & 1) ? 65 : 0, sl = t & 3;
        *(s16x8*)(ldsb + (row*66 + col)*XSTR + sl*16) = (s16x8)0;
    }
    ALOAD(0, 0)
    ALOAD(1, 1)
    stageX(0);
    asm volatile("s_waitcnt lgkmcnt(0)" ::: "memory");
    __builtin_amdgcn_sched_barrier(0);
    __builtin_amdgcn_s_barrier();
    __builtin_amdgcn_sched_barrier(0);

    #pragma unroll
    for (int cc = 0; cc < 4; ++cc) {
        if (cc) {
            __builtin_amdgcn_sched_barrier(0);
            __builtin_amdgcn_s_barrier();            // all waves done reading xbuf
            __builtin_amdgcn_sched_barrier(0);
            stageX(cc);
            asm volatile("s_waitcnt lgkmcnt(0)" ::: "memory");
            __builtin_amdgcn_sched_barrier(0);
            __builtin_amdgcn_s_barrier();            // writes visible to all
            __builtin_amdgcn_sched_barrier(0);
        }
        #pragma unroll
        for (int tap = 0; tap < 9; ++tap) {
            const int it = cc * 9 + tap;
            const int kh = tap / 3;
            const int kw = tap % 3;
            if (it + 2 < 36) {
                switch ((it + 2) % 3) {              // compile-time per unrolled it
                    case 0: ALOAD(it + 2, 0) break;
                    case 1: ALOAD(it + 2, 1) break;
                    case 2: ALOAD(it + 2, 2) break;
                }
            }
            __builtin_amdgcn_sched_barrier(0);       // pin A-issue in this window
            __builtin_amdgcn_s_setprio(1);
            #pragma unroll
            for (int ksub = 0; ksub < 2; ++ksub) {
                const int s = ksub * 2 + khalf;
                s16x8 bv[2];
                #pragma unroll
                for (int nf = 0; nf < 2; ++nf) {
                    const int c = l31 + nf*32 + kw;  // 0..65
                    bv[nf] = *(const s16x8*)(ldsb + ((wn + kh)*66 + c)*XSTR + s*16);
                }
                #pragma unroll
                for (int mf = 0; mf < 2; ++mf)
                    #pragma unroll
                    for (int nf = 0; nf < 2; ++nf)
                        acc[mf][nf] = __builtin_amdgcn_mfma_f32_32x32x16_bf16(
                            aset[it % 3][mf*2 + ksub], bv[nf], acc[mf][nf], 0, 0, 0);
            }
            __builtin_amdgcn_s_setprio(0);
        }
    }
#undef ALOAD

    // store: D col(px)=l31, row(co) = (reg&3) + 8*(reg>>2) + 4*khalf
    #pragma unroll
    for (int nf = 0; nf < 2; ++nf) {
        const int w = nf * 32 + l31;
        if (w < 56) {
            const int hrow = 2 * ph + wn;
            #pragma unroll
            for (int mf = 0; mf < 2; ++mf) {
                #pragma unroll
                for (int rg = 0; rg < 16; ++rg) {
                    int co = wm*64 + mf*32 + (rg & 3) + 8*(rg >> 2) + 4*khalf;
                    out[(((size_t)b*COUT + co)*HH + hrow)*WW + w] = acc[mf][nf][rg];
                }
            }
        }
    }
}

extern "C" void kernel_launch(void* const* d_in, const int* in_sizes, int n_in,
                              void* d_out, int out_size, void* d_ws, size_t ws_size,
                              hipStream_t stream) {
    const float* x = (const float*)d_in[0];          // [16,128,56,56]
    const float* r = (const float*)d_in[1];          // [16,4]
    const float* W = (const float*)d_in[2];          // [4,128,128,3,3]
    float* outp = (float*)d_out;                     // [16,128,56,56]
    u16* Wmix = (u16*)d_ws;                          // 4.72 MB

    mix_kernel<<<576, 256, 0, stream>>>(W, r, Wmix);
    conv_mfma <<<448, 256, 0, stream>>>(x, Wmix, outp);
}

// Round 11
// 34.466 us; speedup vs baseline: 1.2030x; 1.2030x over previous
//
#include <hip/hip_runtime.h>

// CondConv2d B=16,CIN=COUT=128,H=W=56,E=4,3x3,pad=1 fp32.
// (1) mix: fold routing into bf16 Wmix[b][cc][tap][co][ci_l] (conv linear in W).
// (2) conv: block=(b,h-pair): 128co x 128px x K=1152 GEMM on mfma_32x32x16_bf16.
//     512 threads / 8 waves (2co x 2row x 2px) -> 16 waves/CU co-resident:
//     TLP hides A-DMA latency (m114 regime). A: global_load_lds 4-buf counted
//     vmcnt pipeline (1 instr/window). B: x staged fp32->bf16 in LDS per
//     ci-chunk, 72B row stride (2-way banks = free).

typedef float  f32x16 __attribute__((ext_vector_type(16)));
typedef short  s16x8  __attribute__((ext_vector_type(8)));
typedef unsigned short u16;

#define CIN   128
#define COUT  128
#define HH    56
#define WW    56
#define SP    (HH*WW)          // 3136
#define EW    147456           // per-expert W elems
#define BW_   147456           // per-sample Wmix elems: [cc4][tap9][co128][ci32]
#define XSTR  72               // xbuf row stride bytes (64 data + 8 pad)
#define XB    (4*66*XSTR)      // 19008 B
#define AB    8192             // one A slab: 128 co x 32 ci bf16

static __device__ __forceinline__ u16 f2bf(float f) {
    unsigned u = __builtin_bit_cast(unsigned, f);
    return (u16)((u + 0x7FFFu + ((u >> 16) & 1u)) >> 16);
}

static __device__ __forceinline__ void gload16(const void* g, void* l) {
    __builtin_amdgcn_global_load_lds(
        (const __attribute__((address_space(1))) void*)g,
        (__attribute__((address_space(3))) void*)l, 16, 0, 0);
}

// ---------------------------------------------------------------------------
// mix: Wmix[b][cc][tap][co][ci_l] = sum_e r[b,e]*W[e][co][cc*32+ci_l][tap]
// ---------------------------------------------------------------------------
__global__ __launch_bounds__(256) void mix_kernel(const float* __restrict__ W,
                                                  const float* __restrict__ r,
                                                  u16* __restrict__ Wmix) {
    int o = blockIdx.x * 256 + threadIdx.x;      // [0, 147456)
    int ci_l = o & 31;
    int o2   = o >> 5;
    int co   = o2 & 127;
    int o3   = o2 >> 7;                          // [0,36)
    int tap  = o3 % 9;
    int cc   = o3 / 9;
    size_t src = ((size_t)co * CIN + cc*32 + ci_l) * 9 + tap;
    float w0 = W[src], w1 = W[src + EW], w2 = W[src + 2*EW], w3 = W[src + 3*EW];
    #pragma unroll
    for (int b = 0; b < 16; ++b) {
        float acc = r[b*4+0]*w0 + r[b*4+1]*w1 + r[b*4+2]*w2 + r[b*4+3]*w3;
        Wmix[(size_t)b * BW_ + o] = f2bf(acc);
    }
}

// ---------------------------------------------------------------------------
// conv: block=(b, h-pair ph), 512 thr = 8 waves: wm(co half) x wn(row) x wp(px).
// Wave: 64co x 32px. 36 windows (cc,tap): stageA(it+2) [1 gload16/wave];
// vmcnt(2); barrier; 6 ds_read_b128 + 4 MFMA. xbuf restaged per cc.
// A swizzle: LDS[row][slot] = global[row][slot ^ ((row>>1)&3)] (src-side inv).
// LDS: 19008 + 4*8192 = 51776 B -> 2 blocks/CU (16 waves/CU).
// ---------------------------------------------------------------------------
__global__ __launch_bounds__(512, 4) void conv_mfma(const float* __restrict__ x,
                                                    const u16* __restrict__ Wmix,
                                                    float* __restrict__ out) {
    __shared__ __align__(16) char ldsb[XB + 4*AB];

    const int bid = blockIdx.x;
    const int bs  = (bid & 7) * 56 + (bid >> 3);     // bijective XCD swizzle (448=8*56)
    const int b   = bs / 28;
    const int ph  = bs % 28;                         // rows {2ph, 2ph+1}
    const int t    = threadIdx.x;
    const int lane = t & 63;
    const int wid  = t >> 6;                         // 0..7
    const int wm   = (wid >> 2) & 1;                 // co half
    const int wn   = (wid >> 1) & 1;                 // output row within pair
    const int wp   = wid & 1;                        // px half
    const int l31  = lane & 31;
    const int khalf= lane >> 5;

    const u16*   WmixB = Wmix + (size_t)b * BW_;
    const float* xbB   = x + (size_t)b * CIN * SP;

    // A DMA: lane source row = t>>2, dest slot = t&3, src slot inverse-swizzled
    const int ssl = (t & 3) ^ ((t >> 3) & 3);

    f32x16 acc[2];
    acc[0] = (f32x16)0.f;
    acc[1] = (f32x16)0.f;

    auto stageA = [&](int it) {
        char* ldst = ldsb + XB + (it & 3) * AB + wid * 1024;   // wave-uniform base
        const u16* ga = WmixB + it * 4096 + (t >> 2) * 32 + ssl * 8;
        gload16(ga, ldst);
    };

    // B staging: xbuf[row 0..3][col 0..65][32 ci] bf16 for ci-chunk cc
    auto stageX = [&](int cc) {
        #pragma unroll
        for (int i = 0; i < 2; ++i) {
            int slot = i * 512 + t;                  // 0..1023
            int c    = 1 + (slot & 63);              // col 1..64
            int row  = (slot >> 6) & 3;              // 0..3
            int g    = slot >> 8;                    // ci group 0..3
            int rr   = 2*ph - 1 + row;               // input row
            int w    = c - 1;
            bool ok  = ((unsigned)rr < 56u) && (w < 56);
            const float* p = xbB + (size_t)(cc*32 + g*8) * SP + rr*56 + w;
            s16x8 v;
            #pragma unroll
            for (int j = 0; j < 8; ++j) {
                float f = ok ? p[(size_t)j * SP] : 0.f;
                v[j] = (short)f2bf(f);
            }
            *(s16x8*)(ldsb + (row*66 + c)*XSTR + g*16) = v;
        }
    };

    auto compute = [&](int it, int kh, int kw) {
        const char* Ab = ldsb + XB + (it & 3) * AB;
        #pragma unroll
        for (int ksub = 0; ksub < 2; ++ksub) {
            const int s = ksub * 2 + khalf;
            s16x8 af[2], bv;
            #pragma unroll
            for (int mf = 0; mf < 2; ++mf)
                af[mf] = *(const s16x8*)(Ab + (wm*64 + mf*32 + l31)*64
                                            + ((s ^ ((l31 >> 1) & 3)) * 16));
            const int c = wp*32 + l31 + kw;          // 0..65
            bv = *(const s16x8*)(ldsb + ((wn + kh)*66 + c)*XSTR + s*16);
            #pragma unroll
            for (int mf = 0; mf < 2; ++mf)
                acc[mf] = __builtin_amdgcn_mfma_f32_32x32x16_bf16(
                    af[mf], bv, acc[mf], 0, 0, 0);
        }
    };

    // --- prologue: zero halo cols (c=0,65); A slabs 0,1; x chunk 0 ---
    if (t < 32) {
        int row = t >> 3, col = ((t >> 2) & 1) ? 65 : 0, sl = t & 3;
        *(s16x8*)(ldsb + (row*66 + col)*XSTR + sl*16) = (s16x8)0;
    }
    stageA(0);
    stageA(1);
    stageX(0);
    asm volatile("s_waitcnt lgkmcnt(0)" ::: "memory");
    __builtin_amdgcn_sched_barrier(0);
    __builtin_amdgcn_s_barrier();
    __builtin_amdgcn_sched_barrier(0);

    #pragma unroll
    for (int cc = 0; cc < 4; ++cc) {
        if (cc) {
            __builtin_amdgcn_sched_barrier(0);
            __builtin_amdgcn_s_barrier();            // all waves done reading xbuf
            __builtin_amdgcn_sched_barrier(0);
            stageX(cc);
            asm volatile("s_waitcnt lgkmcnt(0)" ::: "memory");
            __builtin_amdgcn_sched_barrier(0);
            __builtin_amdgcn_s_barrier();            // xbuf writes visible
            __builtin_amdgcn_sched_barrier(0);
        }
        #pragma unroll
        for (int tap = 0; tap < 9; ++tap) {
            const int it = cc * 9 + tap;
            if (it + 2 < 36) {
                stageA(it + 2);                      // 1 DMA instr per wave
                asm volatile("s_waitcnt vmcnt(2)" ::: "memory");  // it's slab landed
            } else if (it + 1 < 36) {
                asm volatile("s_waitcnt vmcnt(1)" ::: "memory");
            } else {
                asm volatile("s_waitcnt vmcnt(0)" ::: "memory");
            }
            __builtin_amdgcn_s_barrier();
            __builtin_amdgcn_sched_barrier(0);
            __builtin_amdgcn_s_setprio(1);
            compute(it, tap / 3, tap % 3);
            __builtin_amdgcn_s_setprio(0);
        }
    }

    // store: D col(px)=l31, row(co) = (reg&3) + 8*(reg>>2) + 4*khalf
    const int w = wp * 32 + l31;
    if (w < 56) {
        const int hrow = 2 * ph + wn;
        #pragma unroll
        for (int mf = 0; mf < 2; ++mf) {
            #pragma unroll
            for (int rg = 0; rg < 16; ++rg) {
                int co = wm*64 + mf*32 + (rg & 3) + 8*(rg >> 2) + 4*khalf;
                out[(((size_t)b*COUT + co)*HH + hrow)*WW + w] = acc[mf][rg];
            }
        }
    }
}

extern "C" void kernel_launch(void* const* d_in, const int* in_sizes, int n_in,
                              void* d_out, int out_size, void* d_ws, size_t ws_size,
                              hipStream_t stream) {
    const float* x = (const float*)d_in[0];          // [16,128,56,56]
    const float* r = (const float*)d_in[1];          // [16,4]
    const float* W = (const float*)d_in[2];          // [4,128,128,3,3]
    float* outp = (float*)d_out;                     // [16,128,56,56]
    u16* Wmix = (u16*)d_ws;                          // 4.72 MB

    mix_kernel<<<576, 256, 0, stream>>>(W, r, Wmix);
    conv_mfma <<<448, 512, 0, stream>>>(x, Wmix, outp);
}